// Round 2
// baseline (449.039 us; speedup 1.0000x reference)
//
#include <hip/hip_runtime.h>
#include <hip/hip_bf16.h>
#include <cstdint>

// Problem constants (B, L, D, H from the reference)
#define BB 4
#define LL 4096
#define DD 1024
#define HH 16
#define DKH 64
#define MROWS 16384   // B*L
#define KTOP 8
#define RPB 16        // rows per k_means block

typedef float f32x4 __attribute__((ext_vector_type(4)));
typedef _Float16 f16;
typedef _Float16 f16x4 __attribute__((ext_vector_type(4)));
typedef _Float16 f16x8 __attribute__((ext_vector_type(8)));

// ---------------------------------------------------------------------------
// async global->LDS (16B per lane, wave-uniform LDS base + lane*16)
__device__ __forceinline__ void gll16(const void* g, void* l) {
    __builtin_amdgcn_global_load_lds(
        (const __attribute__((address_space(1))) void*)g,
        (__attribute__((address_space(3))) void*)l, 16, 0, 0);
}

// DPP cross-lane move: returns src value from the partner lane per CTRL.
// 0xB1 = quad_perm(1,0,3,2) -> xor1; 0x4E = quad_perm(2,3,0,1) -> xor2;
// 0x128 = row_ror:8 -> xor8 (rotation by half a 16-row == xor 8).
template <int CTRL>
__device__ __forceinline__ float dppf(float x) {
    return __builtin_bit_cast(float,
        __builtin_amdgcn_update_dpp(0, __builtin_bit_cast(int, x), CTRL, 0xF, 0xF, true));
}

// ---------------------------------------------------------------------------
// Per-head column means of Wq/Wk (mean over DK cols of each head) -> Wqm_t[h][d]
// plus per-head means of bq/bk. Exactness here protects top-k selection.
__global__ void k_colmeans(const float* __restrict__ Wq, const float* __restrict__ bq,
                           const float* __restrict__ Wk, const float* __restrict__ bk,
                           float* __restrict__ Wqm_t, float* __restrict__ Wkm_t,
                           float* __restrict__ bqm, float* __restrict__ bkm) {
    int t = blockIdx.x * blockDim.x + threadIdx.x;   // 0..32767
    int which = t >> 14;                             // 0=q 1=k
    int idx = t & 16383;
    int d = idx >> 4;
    int h = idx & 15;
    const float* W = which ? Wk : Wq;
    const float* p = W + d * DD + h * DKH;
    float s = 0.f;
    #pragma unroll
    for (int c = 0; c < DKH; ++c) s += p[c];
    (which ? Wkm_t : Wqm_t)[h * DD + d] = s * (1.0f / DKH);
    if (d == 0) {
        const float* bb = which ? bk : bq;
        float sb = 0.f;
        for (int c = 0; c < DKH; ++c) sb += bb[h * DKH + c];
        (which ? bkm : bqm)[h] = sb * (1.0f / DKH);
    }
}

// ---------------------------------------------------------------------------
// Transpose 1024x1024 fp32 -> f16 (out[n][k] = in[k][n]) via LDS tile.
__global__ void k_transpose_cvt(const float* __restrict__ in, f16* __restrict__ out) {
    __shared__ float tile[32][33];
    int k0 = blockIdx.x * 32;
    int n0 = blockIdx.y * 32;
    int tx = threadIdx.x, ty = threadIdx.y;
    #pragma unroll
    for (int j = 0; j < 32; j += 8)
        tile[ty + j][tx] = in[(k0 + ty + j) * DD + n0 + tx];
    __syncthreads();
    #pragma unroll
    for (int j = 0; j < 32; j += 8)
        out[(n0 + ty + j) * DD + k0 + tx] = (f16)tile[tx][ty + j];
}

// fp32 -> f16, 4 elems/thread
__global__ void k_cvt_f16(const float* __restrict__ in, f16* __restrict__ out) {
    int i = blockIdx.x * blockDim.x + threadIdx.x;
    f32x4 v = ((const f32x4*)in)[i];
    f16x4 o;
    o[0] = (f16)v.x; o[1] = (f16)v.y; o[2] = (f16)v.z; o[3] = (f16)v.w;
    ((f16x4*)out)[i] = o;
}

// ---------------------------------------------------------------------------
// k_means v4: qm[bh][l], km[bh][l] in fp32.
// Thread (wave w, lane l) owns 4 fixed cols c = w*256 + l*4 and ALL 16 heads.
// W frag = 16 f32x4 = 64 VGPRs, loaded ONCE and pinned in registers via an
// empty asm. DPP butterfly for xor1/xor2/xor8 + one ds_swizzle for xor4.
// Head mapping: lane bits {0,1,3,2} -> head bits {0,1,2,3}.
__global__ __launch_bounds__(256, 4) void k_means(const float* __restrict__ q, const float* __restrict__ k,
                        const float* __restrict__ Wqm_t, const float* __restrict__ Wkm_t,
                        const float* __restrict__ bqm, const float* __restrict__ bkm,
                        float* __restrict__ qm, float* __restrict__ km) {
    __shared__ float lred[RPB * 264];   // 16.9 KB, stride 264 spreads combine banks
    int isK = blockIdx.x & 1;
    int rb  = blockIdx.x >> 1;            // 0..1023
    const float* src = isK ? k : q;
    const float* W   = isK ? Wkm_t : Wqm_t;
    const float* bm  = isK ? bkm : bqm;
    float* dst = isK ? km : qm;
    int t = threadIdx.x;
    int wavei = t >> 6, lane = t & 63;
    int c = wavei * 256 + lane * 4;       // this thread's 4 columns
    f32x4 wr[16];
    #pragma unroll
    for (int h = 0; h < 16; ++h) wr[h] = *(const f32x4*)(W + h * DD + c);
    #pragma unroll
    for (int h = 0; h < 16; ++h) asm volatile("" : "+v"(wr[h]));  // pin in VGPRs
    const float* rbase = src + (size_t)rb * RPB * DD + c;
    f32x4 rv = *(const f32x4*)rbase;
    #pragma unroll
    for (int r = 0; r < RPB; ++r) {
        f32x4 nxt = rv;
        if (r + 1 < RPB) nxt = *(const f32x4*)(rbase + (r + 1) * DD);
        float v[16];
        #pragma unroll
        for (int h = 0; h < 16; ++h)
            v[h] = rv.x * wr[h].x + rv.y * wr[h].y + rv.z * wr[h].z + rv.w * wr[h].w;
        // xor1 (DPP quad_perm): head bit0 = lane bit0
        float u[8];
        #pragma unroll
        for (int i = 0; i < 8; ++i) {
            float keep = (lane & 1) ? v[2*i+1] : v[2*i];
            float send = (lane & 1) ? v[2*i]   : v[2*i+1];
            u[i] = keep + dppf<0xB1>(send);
        }
        // xor2 (DPP quad_perm): head bit1 = lane bit1
        float w2[4];
        #pragma unroll
        for (int i = 0; i < 4; ++i) {
            float keep = (lane & 2) ? u[2*i+1] : u[2*i];
            float send = (lane & 2) ? u[2*i]   : u[2*i+1];
            w2[i] = keep + dppf<0x4E>(send);
        }
        // xor8 (DPP row_ror:8): head bit2 = lane bit3
        float y[2];
        #pragma unroll
        for (int i = 0; i < 2; ++i) {
            float keep = (lane & 8) ? w2[2*i+1] : w2[2*i];
            float send = (lane & 8) ? w2[2*i]   : w2[2*i+1];
            y[i] = keep + dppf<0x128>(send);
        }
        // xor4 (single ds_swizzle): head bit3 = lane bit2
        {
            float keep = (lane & 4) ? y[1] : y[0];
            float send = (lane & 4) ? y[0] : y[1];
            float z = keep + __shfl_xor(send, 4);
            lred[r * 264 + wavei * 64 + lane] = z;
        }
        rv = nxt;
    }
    __syncthreads();
    // combine: 256 outputs (16 rows x 16 heads); sum 4 waves x 4 lane-groups
    int rr = t >> 4, h = t & 15;
    int lp = (h & 3) | (((h >> 2) & 1) << 3) | (((h >> 3) & 1) << 2);
    float s = bm[h];
    #pragma unroll
    for (int w = 0; w < 4; ++w)
        #pragma unroll
        for (int g = 0; g < 4; ++g)
            s += lred[rr * 264 + w * 64 + g * 16 + lp];
    int row = rb * RPB + rr;
    int b = row >> 12, l = row & 4095;
    dst[((size_t)((b << 4) + h) << 12) + l] = s;
}

// ---------------------------------------------------------------------------
// k_corr v3: corr[bh][d] = sum_m qm[bh][(m+d)%L] * km[bh][m]
// 256 blocks x 1024 threads. kv is wave-uniform -> scalar-path global read.
__global__ __launch_bounds__(1024) void k_corr(const float* __restrict__ qm,
                                               const float* __restrict__ km,
                                               float* __restrict__ corr) {
    __shared__ float sq[LL];        // 16 KB
    __shared__ f32x4 red[1024];     // 16 KB
    int bh = blockIdx.x >> 2;
    int lag0 = (blockIdx.x & 3) * 1024;
    const f32x4* qg = (const f32x4*)(qm + bh * LL);
    const f32x4* kg = (const f32x4*)(km + bh * LL);
    f32x4* sq4 = (f32x4*)sq;
    int t = threadIdx.x;
    for (int i = t; i < LL / 4; i += 1024) sq4[i] = qg[i];
    __syncthreads();
    int lt = t & 255;
    int ms = t >> 8;
    int d0 = lag0 + lt * 4;
    int m0 = ms * 1024;
    float a0 = 0, a1 = 0, a2 = 0, a3 = 0;
    f32x4 wv = sq4[((m0 + d0) & 4095) >> 2];
    float w0 = wv.x, w1 = wv.y, w2 = wv.z, w3 = wv.w;
    #pragma unroll 4
    for (int m = m0; m < m0 + 1024; m += 4) {
        f32x4 nx = sq4[((m + 4 + d0) & 4095) >> 2];
        int mi = __builtin_amdgcn_readfirstlane(m >> 2);   // wave-uniform index
        f32x4 kv = kg[mi];
        a0 += kv.x * w0;  a1 += kv.x * w1;  a2 += kv.x * w2;  a3 += kv.x * w3;
        a0 += kv.y * w1;  a1 += kv.y * w2;  a2 += kv.y * w3;  a3 += kv.y * nx.x;
        a0 += kv.z * w2;  a1 += kv.z * w3;  a2 += kv.z * nx.x; a3 += kv.z * nx.y;
        a0 += kv.w * w3;  a1 += kv.w * nx.x; a2 += kv.w * nx.y; a3 += kv.w * nx.z;
        w0 = nx.x; w1 = nx.y; w2 = nx.z; w3 = nx.w;
    }
    f32x4 p; p.x = a0; p.y = a1; p.z = a2; p.w = a3;
    red[t] = p;
    __syncthreads();
    if (t < 256) {
        f32x4 s0 = red[t], s1 = red[256 + t], s2 = red[512 + t], s3 = red[768 + t];
        f32x4 s;
        s.x = s0.x + s1.x + s2.x + s3.x;
        s.y = s0.y + s1.y + s2.y + s3.y;
        s.z = s0.z + s1.z + s2.z + s3.z;
        s.w = s0.w + s1.w + s2.w + s3.w;
        *(f32x4*)(corr + bh * LL + lag0 + t * 4) = s;
    }
}

// ---------------------------------------------------------------------------
// top-8 (value, index) per bh with lowest-index tie-break, then softmax.
__global__ __launch_bounds__(256) void k_topk(const float* __restrict__ corr,
                                              float* __restrict__ wts, int* __restrict__ dls) {
    __shared__ float sc[LL];
    __shared__ float rv[4]; __shared__ int ri[4];
    __shared__ float topv[KTOP]; __shared__ int topi[KTOP];
    int bh = blockIdx.x;
    for (int i = threadIdx.x; i < LL; i += 256) sc[i] = corr[bh * LL + i];
    for (int kk = 0; kk < KTOP; ++kk) {
        __syncthreads();
        float bv = -1e30f; int bi = 0;
        for (int i = threadIdx.x; i < LL; i += 256) {
            float v = sc[i];
            if (v > bv) { bv = v; bi = i; }
        }
        #pragma unroll
        for (int off = 32; off; off >>= 1) {
            float ov = __shfl_down(bv, off);
            int oi = __shfl_down(bi, off);
            if (ov > bv || (ov == bv && oi < bi)) { bv = ov; bi = oi; }
        }
        int wid = threadIdx.x >> 6;
        if ((threadIdx.x & 63) == 0) { rv[wid] = bv; ri[wid] = bi; }
        __syncthreads();
        if (threadIdx.x == 0) {
            for (int w = 1; w < 4; ++w)
                if (rv[w] > bv || (rv[w] == bv && ri[w] < bi)) { bv = rv[w]; bi = ri[w]; }
            topv[kk] = bv; topi[kk] = bi;
            sc[bi] = -1e30f;
        }
    }
    __syncthreads();
    if (threadIdx.x == 0) {
        float mx = topv[0], s = 0.f, e[KTOP];
        #pragma unroll
        for (int kk = 0; kk < KTOP; ++kk) { e[kk] = __expf(topv[kk] - mx); s += e[kk]; }
        float inv = 1.0f / s;
        #pragma unroll
        for (int kk = 0; kk < KTOP; ++kk) {
            wts[bh * KTOP + kk] = e[kk] * inv;
            dls[bh * KTOP + kk] = topi[kk];
        }
    }
}

// ---------------------------------------------------------------------------
// f16 MFMA GEMM v2: C = A(MxK) @ BT(NxK)^T + bias. 128x128 tile, BK=32,
// 4 waves, DOUBLE-BUFFERED 2-phase pipeline (T3-minimum):
//   prologue: STAGE(buf0); barrier;
//   loop:     STAGE(buf^1, t+1); ds_read+MFMA(buf, t); barrier;  (1 barrier/step)
//   epilogue: compute last tile.
// The __syncthreads() drain (vmcnt0+lgkmcnt0) provides all ordering: stage of
// t+1 is issued BEFORE compute of t, so HBM/L2 latency hides under 16 MFMAs
// x 4 waves. Round-1 counters proved the old stage->drain->compute loop was
// latency-bound, not HBM-bound (FETCH fell 3x, time unchanged, MfmaUtil 21%).
// LDS tiles: 16B chunks row-major, XOR swizzle kc^((row>>1)&3) -> staging
// 64B-coalesced, fragment ds_read_b128 2-way (free).
// Grid mapping: blockIdx.x = M-tile (fastest) so blocks sharing an A-panel
// land on the SAME XCD (A fetched once per chip).
// MODE 0: store f16 into V[b][h][l][c] (BHLD).  MODE 1: store fp32 row-major.
#define BM 128
#define BN 128
#define BKK 32
template <int MODE>
__global__ __launch_bounds__(256) void k_gemm_bt(const f16* __restrict__ A,
                                                 const f16* __restrict__ BT,
                                                 const float* __restrict__ bias,
                                                 void* __restrict__ Cout) {
    __shared__ f16 As[2][BM * BKK];   // 2 x 8 KB
    __shared__ f16 Bs[2][BN * BKK];   // 2 x 8 KB
    const int K = DD;
    int m0 = blockIdx.x * BM;
    int n0 = blockIdx.y * BN;
    int tid = threadIdx.x;
    int lane = tid & 63;
    int wave = tid >> 6;
    int wm = wave & 1, wn = wave >> 1;

    // staging source (two passes of 256 chunks)
    int row0 = tid >> 2;                 // 0..63
    int slot = tid & 3;
    int kc0 = slot ^ ((row0 >> 1) & 3);
    int row1 = row0 + 64;                // 64..127
    int kc1 = slot ^ ((row1 >> 1) & 3);
    const f16* gA0 = A + (size_t)(m0 + row0) * K + kc0 * 8;
    const f16* gA1 = A + (size_t)(m0 + row1) * K + kc1 * 8;
    const f16* gB0 = BT + (size_t)(n0 + row0) * K + kc0 * 8;
    const f16* gB1 = BT + (size_t)(n0 + row1) * K + kc1 * 8;

    // fragment LDS element offsets (constant per lane)
    int fr = lane & 15;
    int quad = lane >> 4;
    int a_off[4], b_off[4];
    #pragma unroll
    for (int i = 0; i < 4; ++i) {
        int ra = wm * 64 + i * 16 + fr;
        a_off[i] = (ra * 4 + (quad ^ ((ra >> 1) & 3))) * 8;
        int rb = wn * 64 + i * 16 + fr;
        b_off[i] = (rb * 4 + (quad ^ ((rb >> 1) & 3))) * 8;
    }

    f32x4 acc[4][4] = {};

    auto STAGE = [&](int b) {
        char* la = (char*)As + b * 8192 + wave * 1024;
        char* lb = (char*)Bs + b * 8192 + wave * 1024;
        gll16(gA0, la);
        gll16(gA1, la + 4096);
        gll16(gB0, lb);
        gll16(gB1, lb + 4096);
        gA0 += BKK; gA1 += BKK; gB0 += BKK; gB1 += BKK;
    };
    auto COMPUTE = [&](int b) {
        const f16* Ab = As[b];
        const f16* Bb = Bs[b];
        f16x8 af[4], bf[4];
        #pragma unroll
        for (int i = 0; i < 4; ++i) af[i] = *(const f16x8*)(Ab + a_off[i]);
        #pragma unroll
        for (int i = 0; i < 4; ++i) bf[i] = *(const f16x8*)(Bb + b_off[i]);
        #pragma unroll
        for (int im = 0; im < 4; ++im)
            #pragma unroll
            for (int in = 0; in < 4; ++in)
                acc[im][in] = __builtin_amdgcn_mfma_f32_16x16x32_f16(af[im], bf[in], acc[im][in], 0, 0, 0);
    };

    STAGE(0);
    __syncthreads();                    // vmcnt(0) drain: buf0 ready
    const int NT = K / BKK;             // 32
    for (int kt = 0; kt < NT - 1; ++kt) {
        STAGE((kt & 1) ^ 1);            // issue next-tile loads FIRST
        COMPUTE(kt & 1);                // ds_read + MFMA current tile
        __syncthreads();                // drains stage; protects both buffers
    }
    COMPUTE((NT - 1) & 1);              // last tile, no prefetch

    // epilogue: C/D layout col = lane&15, row = quad*4 + reg
    #pragma unroll
    for (int in = 0; in < 4; ++in) {
        int col = n0 + wn * 64 + in * 16 + fr;
        float bb = bias[col];
        #pragma unroll
        for (int im = 0; im < 4; ++im) {
            int rowb = m0 + wm * 64 + im * 16 + quad * 4;
            #pragma unroll
            for (int r = 0; r < 4; ++r) {
                float val = acc[im][in][r] + bb;
                if (MODE == 0) {
                    int rr = rowb + r;
                    int b = rr >> 12, l = rr & 4095, h = col >> 6, c = col & 63;
                    ((f16*)Cout)[((size_t)(((b << 4) + h) << 12) + l) * 64 + c] = (f16)val;
                } else {
                    ((float*)Cout)[(size_t)(rowb + r) * DD + col] = val;
                }
            }
        }
    }
}

// ---------------------------------------------------------------------------
// out[b][l][h*64+c] = sum_k w[bh][k] * V[b][h][(l-d_k)&4095][c], f16 in/out.
// XCD-grouped block mapping: each bh's V-slice is 512 KB read 8x (shifted).
// Group all 128 blocks of a bh onto ONE XCD (8 bh per XCD = 4 MB = one L2)
// so each bh is fetched from HBM once chip-wide instead of once per XCD.
__global__ __launch_bounds__(256) void k_roll(const f16* __restrict__ V,
                                              const float* __restrict__ wts,
                                              const int* __restrict__ dls,
                                              f16* __restrict__ out) {
    int x = blockIdx.x;
    int wk = ((x & 7) << 10) | (x >> 3);       // bijective: 8192 = 8 x 1024
    int t = wk * 256 + threadIdx.x;            // B*H*L*8 threads
    int cc = t & 7;
    int l = (t >> 3) & 4095;
    int bh = t >> 15;
    const f16* vb = V + ((size_t)bh << 18);
    float a[8] = {};
    #pragma unroll
    for (int kk = 0; kk < KTOP; ++kk) {
        float w = wts[bh * KTOP + kk];
        int d = dls[bh * KTOP + kk];
        int src = (l - d) & 4095;
        f16x8 vv = *(const f16x8*)(vb + (src << 6) + (cc << 3));
        #pragma unroll
        for (int j = 0; j < 8; ++j) a[j] += w * (float)vv[j];
    }
    f16* o = out + ((size_t)((bh >> 4) << 12) + l) * 1024 + ((bh & 15) << 6) + (cc << 3);
    f16x8 ov;
    #pragma unroll
    for (int j = 0; j < 8; ++j) ov[j] = (f16)a[j];
    *(f16x8*)o = ov;
}

// ---------------------------------------------------------------------------
extern "C" void kernel_launch(void* const* d_in, const int* in_sizes, int n_in,
                              void* d_out, int out_size, void* d_ws, size_t ws_size,
                              hipStream_t stream) {
    const float* queries = (const float*)d_in[0];
    const float* keys    = (const float*)d_in[1];
    const float* values  = (const float*)d_in[2];
    const float* Wq = (const float*)d_in[3];
    const float* bq = (const float*)d_in[4];
    const float* Wk = (const float*)d_in[5];
    const float* bk = (const float*)d_in[6];
    const float* Wv = (const float*)d_in[7];
    const float* bv = (const float*)d_in[8];
    const float* Wo = (const float*)d_in[9];
    const float* bo = (const float*)d_in[10];

    char* ws = (char*)d_ws;
    size_t off = 0;
    auto alloc = [&](size_t bytes) -> char* {
        char* p = ws + off;
        off += (bytes + 255) & ~(size_t)255;
        return p;
    };
    f16*   values_f16 = (f16*)alloc((size_t)MROWS * DD * 2);  // 33.5 MB
    f16*   Vbuf       = (f16*)alloc((size_t)MROWS * DD * 2);  // 33.5 MB
    f16*   WvT        = (f16*)alloc((size_t)DD * DD * 2);
    f16*   WoT        = (f16*)alloc((size_t)DD * DD * 2);
    float* Wqm_t      = (float*)alloc(HH * DD * 4);
    float* Wkm_t      = (float*)alloc(HH * DD * 4);
    float* bqm        = (float*)alloc(HH * 4);
    float* bkm        = (float*)alloc(HH * 4);
    float* qm         = (float*)alloc((size_t)BB * HH * LL * 4);
    float* km         = (float*)alloc((size_t)BB * HH * LL * 4);
    float* corr       = (float*)alloc((size_t)BB * HH * LL * 4);
    float* wts        = (float*)alloc(BB * HH * KTOP * 4);
    int*   dls        = (int*)alloc(BB * HH * KTOP * 4);
    f16*   out_f16    = values_f16;  // alias: values_f16 is dead after GEMM1

    k_colmeans<<<128, 256, 0, stream>>>(Wq, bq, Wk, bk, Wqm_t, Wkm_t, bqm, bkm);
    k_transpose_cvt<<<dim3(32, 32), dim3(32, 8), 0, stream>>>(Wv, WvT);
    k_transpose_cvt<<<dim3(32, 32), dim3(32, 8), 0, stream>>>(Wo, WoT);
    k_cvt_f16<<<16384, 256, 0, stream>>>(values, values_f16);
    k_means<<<2048, 256, 0, stream>>>(queries, keys, Wqm_t, Wkm_t, bqm, bkm, qm, km);
    k_corr<<<256, 1024, 0, stream>>>(qm, km, corr);
    k_topk<<<64, 256, 0, stream>>>(corr, wts, dls);
    k_gemm_bt<0><<<dim3(MROWS / BM, DD / BN), 256, 0, stream>>>(values_f16, WvT, bv, Vbuf);
    k_roll<<<8192, 256, 0, stream>>>(Vbuf, wts, dls, out_f16);
    k_gemm_bt<1><<<dim3(MROWS / BM, DD / BN), 256, 0, stream>>>(out_f16, WoT, bo, d_out);
}

// Round 3
// 437.208 us; speedup vs baseline: 1.0271x; 1.0271x over previous
//
#include <hip/hip_runtime.h>
#include <hip/hip_bf16.h>
#include <cstdint>

// Problem constants (B, L, D, H from the reference)
#define BB 4
#define LL 4096
#define DD 1024
#define HH 16
#define DKH 64
#define MROWS 16384   // B*L
#define KTOP 8
#define RPB 16        // rows per k_means block

typedef float f32x4 __attribute__((ext_vector_type(4)));
typedef _Float16 f16;
typedef _Float16 f16x4 __attribute__((ext_vector_type(4)));
typedef _Float16 f16x8 __attribute__((ext_vector_type(8)));

// ---------------------------------------------------------------------------
// async global->LDS (16B per lane, wave-uniform LDS base + lane*16)
__device__ __forceinline__ void gll16(const void* g, void* l) {
    __builtin_amdgcn_global_load_lds(
        (const __attribute__((address_space(1))) void*)g,
        (__attribute__((address_space(3))) void*)l, 16, 0, 0);
}

// DPP cross-lane move: returns src value from the partner lane per CTRL.
// 0xB1 = quad_perm(1,0,3,2) -> xor1; 0x4E = quad_perm(2,3,0,1) -> xor2;
// 0x128 = row_ror:8 -> xor8 (rotation by half a 16-row == xor 8).
template <int CTRL>
__device__ __forceinline__ float dppf(float x) {
    return __builtin_bit_cast(float,
        __builtin_amdgcn_update_dpp(0, __builtin_bit_cast(int, x), CTRL, 0xF, 0xF, true));
}

// ---------------------------------------------------------------------------
// Per-head column means of Wq/Wk (mean over DK cols of each head) -> Wqm_t[h][d]
// plus per-head means of bq/bk. Exactness here protects top-k selection.
__global__ void k_colmeans(const float* __restrict__ Wq, const float* __restrict__ bq,
                           const float* __restrict__ Wk, const float* __restrict__ bk,
                           float* __restrict__ Wqm_t, float* __restrict__ Wkm_t,
                           float* __restrict__ bqm, float* __restrict__ bkm) {
    int t = blockIdx.x * blockDim.x + threadIdx.x;   // 0..32767
    int which = t >> 14;                             // 0=q 1=k
    int idx = t & 16383;
    int d = idx >> 4;
    int h = idx & 15;
    const float* W = which ? Wk : Wq;
    const float* p = W + d * DD + h * DKH;
    float s = 0.f;
    #pragma unroll
    for (int c = 0; c < DKH; ++c) s += p[c];
    (which ? Wkm_t : Wqm_t)[h * DD + d] = s * (1.0f / DKH);
    if (d == 0) {
        const float* bb = which ? bk : bq;
        float sb = 0.f;
        for (int c = 0; c < DKH; ++c) sb += bb[h * DKH + c];
        (which ? bkm : bqm)[h] = sb * (1.0f / DKH);
    }
}

// ---------------------------------------------------------------------------
// Transpose 1024x1024 fp32 -> f16 (out[n][k] = in[k][n]) via LDS tile.
__global__ void k_transpose_cvt(const float* __restrict__ in, f16* __restrict__ out) {
    __shared__ float tile[32][33];
    int k0 = blockIdx.x * 32;
    int n0 = blockIdx.y * 32;
    int tx = threadIdx.x, ty = threadIdx.y;
    #pragma unroll
    for (int j = 0; j < 32; j += 8)
        tile[ty + j][tx] = in[(k0 + ty + j) * DD + n0 + tx];
    __syncthreads();
    #pragma unroll
    for (int j = 0; j < 32; j += 8)
        out[(n0 + ty + j) * DD + k0 + tx] = (f16)tile[tx][ty + j];
}

// fp32 -> f16, 4 elems/thread
__global__ void k_cvt_f16(const float* __restrict__ in, f16* __restrict__ out) {
    int i = blockIdx.x * blockDim.x + threadIdx.x;
    f32x4 v = ((const f32x4*)in)[i];
    f16x4 o;
    o[0] = (f16)v.x; o[1] = (f16)v.y; o[2] = (f16)v.z; o[3] = (f16)v.w;
    ((f16x4*)out)[i] = o;
}

// ---------------------------------------------------------------------------
// k_means v4: qm[bh][l], km[bh][l] in fp32.
// Thread (wave w, lane l) owns 4 fixed cols c = w*256 + l*4 and ALL 16 heads.
// W frag = 16 f32x4 = 64 VGPRs, loaded ONCE and pinned in registers via an
// empty asm. DPP butterfly for xor1/xor2/xor8 + one ds_swizzle for xor4.
// Head mapping: lane bits {0,1,3,2} -> head bits {0,1,2,3}.
__global__ __launch_bounds__(256, 4) void k_means(const float* __restrict__ q, const float* __restrict__ k,
                        const float* __restrict__ Wqm_t, const float* __restrict__ Wkm_t,
                        const float* __restrict__ bqm, const float* __restrict__ bkm,
                        float* __restrict__ qm, float* __restrict__ km) {
    __shared__ float lred[RPB * 264];   // 16.9 KB, stride 264 spreads combine banks
    int isK = blockIdx.x & 1;
    int rb  = blockIdx.x >> 1;            // 0..1023
    const float* src = isK ? k : q;
    const float* W   = isK ? Wkm_t : Wqm_t;
    const float* bm  = isK ? bkm : bqm;
    float* dst = isK ? km : qm;
    int t = threadIdx.x;
    int wavei = t >> 6, lane = t & 63;
    int c = wavei * 256 + lane * 4;       // this thread's 4 columns
    f32x4 wr[16];
    #pragma unroll
    for (int h = 0; h < 16; ++h) wr[h] = *(const f32x4*)(W + h * DD + c);
    #pragma unroll
    for (int h = 0; h < 16; ++h) asm volatile("" : "+v"(wr[h]));  // pin in VGPRs
    const float* rbase = src + (size_t)rb * RPB * DD + c;
    f32x4 rv = *(const f32x4*)rbase;
    #pragma unroll
    for (int r = 0; r < RPB; ++r) {
        f32x4 nxt = rv;
        if (r + 1 < RPB) nxt = *(const f32x4*)(rbase + (r + 1) * DD);
        float v[16];
        #pragma unroll
        for (int h = 0; h < 16; ++h)
            v[h] = rv.x * wr[h].x + rv.y * wr[h].y + rv.z * wr[h].z + rv.w * wr[h].w;
        // xor1 (DPP quad_perm): head bit0 = lane bit0
        float u[8];
        #pragma unroll
        for (int i = 0; i < 8; ++i) {
            float keep = (lane & 1) ? v[2*i+1] : v[2*i];
            float send = (lane & 1) ? v[2*i]   : v[2*i+1];
            u[i] = keep + dppf<0xB1>(send);
        }
        // xor2 (DPP quad_perm): head bit1 = lane bit1
        float w2[4];
        #pragma unroll
        for (int i = 0; i < 4; ++i) {
            float keep = (lane & 2) ? u[2*i+1] : u[2*i];
            float send = (lane & 2) ? u[2*i]   : u[2*i+1];
            w2[i] = keep + dppf<0x4E>(send);
        }
        // xor8 (DPP row_ror:8): head bit2 = lane bit3
        float y[2];
        #pragma unroll
        for (int i = 0; i < 2; ++i) {
            float keep = (lane & 8) ? w2[2*i+1] : w2[2*i];
            float send = (lane & 8) ? w2[2*i]   : w2[2*i+1];
            y[i] = keep + dppf<0x128>(send);
        }
        // xor4 (single ds_swizzle): head bit3 = lane bit2
        {
            float keep = (lane & 4) ? y[1] : y[0];
            float send = (lane & 4) ? y[0] : y[1];
            float z = keep + __shfl_xor(send, 4);
            lred[r * 264 + wavei * 64 + lane] = z;
        }
        rv = nxt;
    }
    __syncthreads();
    // combine: 256 outputs (16 rows x 16 heads); sum 4 waves x 4 lane-groups
    int rr = t >> 4, h = t & 15;
    int lp = (h & 3) | (((h >> 2) & 1) << 3) | (((h >> 3) & 1) << 2);
    float s = bm[h];
    #pragma unroll
    for (int w = 0; w < 4; ++w)
        #pragma unroll
        for (int g = 0; g < 4; ++g)
            s += lred[rr * 264 + w * 64 + g * 16 + lp];
    int row = rb * RPB + rr;
    int b = row >> 12, l = row & 4095;
    dst[((size_t)((b << 4) + h) << 12) + l] = s;
}

// ---------------------------------------------------------------------------
// k_corr v3: corr[bh][d] = sum_m qm[bh][(m+d)%L] * km[bh][m]
// 256 blocks x 1024 threads. kv is wave-uniform -> scalar-path global read.
__global__ __launch_bounds__(1024) void k_corr(const float* __restrict__ qm,
                                               const float* __restrict__ km,
                                               float* __restrict__ corr) {
    __shared__ float sq[LL];        // 16 KB
    __shared__ f32x4 red[1024];     // 16 KB
    int bh = blockIdx.x >> 2;
    int lag0 = (blockIdx.x & 3) * 1024;
    const f32x4* qg = (const f32x4*)(qm + bh * LL);
    const f32x4* kg = (const f32x4*)(km + bh * LL);
    f32x4* sq4 = (f32x4*)sq;
    int t = threadIdx.x;
    for (int i = t; i < LL / 4; i += 1024) sq4[i] = qg[i];
    __syncthreads();
    int lt = t & 255;
    int ms = t >> 8;
    int d0 = lag0 + lt * 4;
    int m0 = ms * 1024;
    float a0 = 0, a1 = 0, a2 = 0, a3 = 0;
    f32x4 wv = sq4[((m0 + d0) & 4095) >> 2];
    float w0 = wv.x, w1 = wv.y, w2 = wv.z, w3 = wv.w;
    #pragma unroll 4
    for (int m = m0; m < m0 + 1024; m += 4) {
        f32x4 nx = sq4[((m + 4 + d0) & 4095) >> 2];
        int mi = __builtin_amdgcn_readfirstlane(m >> 2);   // wave-uniform index
        f32x4 kv = kg[mi];
        a0 += kv.x * w0;  a1 += kv.x * w1;  a2 += kv.x * w2;  a3 += kv.x * w3;
        a0 += kv.y * w1;  a1 += kv.y * w2;  a2 += kv.y * w3;  a3 += kv.y * nx.x;
        a0 += kv.z * w2;  a1 += kv.z * w3;  a2 += kv.z * nx.x; a3 += kv.z * nx.y;
        a0 += kv.w * w3;  a1 += kv.w * nx.x; a2 += kv.w * nx.y; a3 += kv.w * nx.z;
        w0 = nx.x; w1 = nx.y; w2 = nx.z; w3 = nx.w;
    }
    f32x4 p; p.x = a0; p.y = a1; p.z = a2; p.w = a3;
    red[t] = p;
    __syncthreads();
    if (t < 256) {
        f32x4 s0 = red[t], s1 = red[256 + t], s2 = red[512 + t], s3 = red[768 + t];
        f32x4 s;
        s.x = s0.x + s1.x + s2.x + s3.x;
        s.y = s0.y + s1.y + s2.y + s3.y;
        s.z = s0.z + s1.z + s2.z + s3.z;
        s.w = s0.w + s1.w + s2.w + s3.w;
        *(f32x4*)(corr + bh * LL + lag0 + t * 4) = s;
    }
}

// ---------------------------------------------------------------------------
// top-8 (value, index) per bh with lowest-index tie-break, then softmax.
__global__ __launch_bounds__(256) void k_topk(const float* __restrict__ corr,
                                              float* __restrict__ wts, int* __restrict__ dls) {
    __shared__ float sc[LL];
    __shared__ float rv[4]; __shared__ int ri[4];
    __shared__ float topv[KTOP]; __shared__ int topi[KTOP];
    int bh = blockIdx.x;
    for (int i = threadIdx.x; i < LL; i += 256) sc[i] = corr[bh * LL + i];
    for (int kk = 0; kk < KTOP; ++kk) {
        __syncthreads();
        float bv = -1e30f; int bi = 0;
        for (int i = threadIdx.x; i < LL; i += 256) {
            float v = sc[i];
            if (v > bv) { bv = v; bi = i; }
        }
        #pragma unroll
        for (int off = 32; off; off >>= 1) {
            float ov = __shfl_down(bv, off);
            int oi = __shfl_down(bi, off);
            if (ov > bv || (ov == bv && oi < bi)) { bv = ov; bi = oi; }
        }
        int wid = threadIdx.x >> 6;
        if ((threadIdx.x & 63) == 0) { rv[wid] = bv; ri[wid] = bi; }
        __syncthreads();
        if (threadIdx.x == 0) {
            for (int w = 1; w < 4; ++w)
                if (rv[w] > bv || (rv[w] == bv && ri[w] < bi)) { bv = rv[w]; bi = ri[w]; }
            topv[kk] = bv; topi[kk] = bi;
            sc[bi] = -1e30f;
        }
    }
    __syncthreads();
    if (threadIdx.x == 0) {
        float mx = topv[0], s = 0.f, e[KTOP];
        #pragma unroll
        for (int kk = 0; kk < KTOP; ++kk) { e[kk] = __expf(topv[kk] - mx); s += e[kk]; }
        float inv = 1.0f / s;
        #pragma unroll
        for (int kk = 0; kk < KTOP; ++kk) {
            wts[bh * KTOP + kk] = e[kk] * inv;
            dls[bh * KTOP + kk] = topi[kk];
        }
    }
}

// ---------------------------------------------------------------------------
// f16 MFMA GEMM v3: C = A(MxK) @ BT(NxK)^T + bias. 128x128 tile, BK=32,
// 4 waves. 3-buffer stage-2-ahead pipeline with COUNTED vmcnt (T3+T4):
//   prologue: STAGE(tile0->buf0); STAGE(tile1->buf1)
//   iter i:   s_waitcnt vmcnt(4)   (own tile-i loads retired, in-order)
//             s_barrier            (=> tile i complete CU-wide; also proves
//                                   all waves consumed buf((i-1)%3): their
//                                   MFMAs forced lgkm completion pre-barrier)
//             STAGE(tile i+2 -> buf (i+2)%3)   (overwrites buf((i-1)%3): safe)
//             COMPUTE(buf i%3)
//   tail:     vmcnt(4)/vmcnt(0) drains, no stages.
// vmcnt NEVER drains to 0 in the main loop: tile i's loads were issued 2
// iterations (~1100 cyc) earlier, covering the ~900 cyc HBM miss latency that
// round-1 counters showed fully exposed (per-step wall 1200 cyc vs 78 MFMA).
// Buffer indices are compile-time (loop unrolled in groups of 3) so the
// round-2 runtime-index VALU blowup (10%->34% VALUBusy) cannot reappear.
// LDS tiles: 16B chunks row-major, XOR swizzle kc^((row>>1)&3) -> staging
// 64B-coalesced, fragment ds_read_b128 2-way (free).
// Grid mapping: blockIdx.x = M-tile (fastest) -> A-panel-sharing blocks on
// the same XCD (round-1 verified: FETCH 133->42 MB).
// MODE 0: store f16 into V[b][h][l][c] (BHLD).  MODE 1: store fp32 row-major.
#define BM 128
#define BN 128
#define BKK 32
template <int MODE>
__global__ __launch_bounds__(256) void k_gemm_bt(const f16* __restrict__ A,
                                                 const f16* __restrict__ BT,
                                                 const float* __restrict__ bias,
                                                 void* __restrict__ Cout) {
    __shared__ f16 As[3][BM * BKK];   // 3 x 8 KB
    __shared__ f16 Bs[3][BN * BKK];   // 3 x 8 KB
    const int K = DD;
    int m0 = blockIdx.x * BM;
    int n0 = blockIdx.y * BN;
    int tid = threadIdx.x;
    int lane = tid & 63;
    int wave = tid >> 6;
    int wm = wave & 1, wn = wave >> 1;

    // staging source (two passes of 256 chunks), loop-invariant bases
    int row0 = tid >> 2;                 // 0..63
    int slot = tid & 3;
    int kc0 = slot ^ ((row0 >> 1) & 3);
    int row1 = row0 + 64;                // 64..127
    int kc1 = slot ^ ((row1 >> 1) & 3);
    const f16* gA0 = A + (size_t)(m0 + row0) * K + kc0 * 8;
    const f16* gA1 = A + (size_t)(m0 + row1) * K + kc1 * 8;
    const f16* gB0 = BT + (size_t)(n0 + row0) * K + kc0 * 8;
    const f16* gB1 = BT + (size_t)(n0 + row1) * K + kc1 * 8;

    // fragment LDS element offsets (constant per lane)
    int fr = lane & 15;
    int quad = lane >> 4;
    int a_off[4], b_off[4];
    #pragma unroll
    for (int i = 0; i < 4; ++i) {
        int ra = wm * 64 + i * 16 + fr;
        a_off[i] = (ra * 4 + (quad ^ ((ra >> 1) & 3))) * 8;
        int rb = wn * 64 + i * 16 + fr;
        b_off[i] = (rb * 4 + (quad ^ ((rb >> 1) & 3))) * 8;
    }

    f32x4 acc[4][4] = {};

    auto STAGE = [&](int b, int kt) {   // b: compile-time at every call site
        char* la = (char*)(&As[b][0]) + wave * 1024;
        char* lb = (char*)(&Bs[b][0]) + wave * 1024;
        int ko = kt * BKK;
        gll16(gA0 + ko, la);
        gll16(gA1 + ko, la + 4096);
        gll16(gB0 + ko, lb);
        gll16(gB1 + ko, lb + 4096);
    };
    auto COMPUTE = [&](int b) {         // b: compile-time at every call site
        const f16* Ab = &As[b][0];
        const f16* Bb = &Bs[b][0];
        f16x8 af[4], bf[4];
        #pragma unroll
        for (int i = 0; i < 4; ++i) af[i] = *(const f16x8*)(Ab + a_off[i]);
        #pragma unroll
        for (int i = 0; i < 4; ++i) bf[i] = *(const f16x8*)(Bb + b_off[i]);
        #pragma unroll
        for (int im = 0; im < 4; ++im)
            #pragma unroll
            for (int in = 0; in < 4; ++in)
                acc[im][in] = __builtin_amdgcn_mfma_f32_16x16x32_f16(af[im], bf[in], acc[im][in], 0, 0, 0);
    };

    const int NT = K / BKK;             // 32
    STAGE(0, 0);
    STAGE(1, 1);
    for (int ii = 0; ii < NT - 2; ii += 3) {
        // iter ii: compute buf0, stage -> buf2
        asm volatile("s_waitcnt vmcnt(4)" ::: "memory");
        __builtin_amdgcn_s_barrier();
        STAGE(2, ii + 2);
        COMPUTE(0);
        // iter ii+1: compute buf1, stage -> buf0
        asm volatile("s_waitcnt vmcnt(4)" ::: "memory");
        __builtin_amdgcn_s_barrier();
        STAGE(0, ii + 3);
        COMPUTE(1);
        // iter ii+2: compute buf2, stage -> buf1
        asm volatile("s_waitcnt vmcnt(4)" ::: "memory");
        __builtin_amdgcn_s_barrier();
        STAGE(1, ii + 4);
        COMPUTE(2);
    }
    // tail: tiles NT-2 (buf0), NT-1 (buf1); no stages in flight after these
    asm volatile("s_waitcnt vmcnt(4)" ::: "memory");
    __builtin_amdgcn_s_barrier();
    COMPUTE(0);
    asm volatile("s_waitcnt vmcnt(0)" ::: "memory");
    __builtin_amdgcn_s_barrier();
    COMPUTE(1);

    // epilogue: C/D layout col = lane&15, row = quad*4 + reg
    #pragma unroll
    for (int in = 0; in < 4; ++in) {
        int col = n0 + wn * 64 + in * 16 + fr;
        float bb = bias[col];
        #pragma unroll
        for (int im = 0; im < 4; ++im) {
            int rowb = m0 + wm * 64 + im * 16 + quad * 4;
            #pragma unroll
            for (int r = 0; r < 4; ++r) {
                float val = acc[im][in][r] + bb;
                if (MODE == 0) {
                    int rr = rowb + r;
                    int b = rr >> 12, l = rr & 4095, h = col >> 6, c = col & 63;
                    ((f16*)Cout)[((size_t)(((b << 4) + h) << 12) + l) * 64 + c] = (f16)val;
                } else {
                    ((float*)Cout)[(size_t)(rowb + r) * DD + col] = val;
                }
            }
        }
    }
}

// ---------------------------------------------------------------------------
// out[b][l][h*64+c] = sum_k w[bh][k] * V[b][h][(l-d_k)&4095][c], f16 in/out.
// XCD-grouped block mapping: each bh's V-slice is 512 KB read 8x (shifted).
// Group all 128 blocks of a bh onto ONE XCD (8 bh per XCD = 4 MB = one L2)
// so each bh is fetched from HBM once chip-wide instead of once per XCD.
__global__ __launch_bounds__(256) void k_roll(const f16* __restrict__ V,
                                              const float* __restrict__ wts,
                                              const int* __restrict__ dls,
                                              f16* __restrict__ out) {
    int x = blockIdx.x;
    int wk = ((x & 7) << 10) | (x >> 3);       // bijective: 8192 = 8 x 1024
    int t = wk * 256 + threadIdx.x;            // B*H*L*8 threads
    int cc = t & 7;
    int l = (t >> 3) & 4095;
    int bh = t >> 15;
    const f16* vb = V + ((size_t)bh << 18);
    float a[8] = {};
    #pragma unroll
    for (int kk = 0; kk < KTOP; ++kk) {
        float w = wts[bh * KTOP + kk];
        int d = dls[bh * KTOP + kk];
        int src = (l - d) & 4095;
        f16x8 vv = *(const f16x8*)(vb + (src << 6) + (cc << 3));
        #pragma unroll
        for (int j = 0; j < 8; ++j) a[j] += w * (float)vv[j];
    }
    f16* o = out + ((size_t)((bh >> 4) << 12) + l) * 1024 + ((bh & 15) << 6) + (cc << 3);
    f16x8 ov;
    #pragma unroll
    for (int j = 0; j < 8; ++j) ov[j] = (f16)a[j];
    *(f16x8*)o = ov;
}

// ---------------------------------------------------------------------------
extern "C" void kernel_launch(void* const* d_in, const int* in_sizes, int n_in,
                              void* d_out, int out_size, void* d_ws, size_t ws_size,
                              hipStream_t stream) {
    const float* queries = (const float*)d_in[0];
    const float* keys    = (const float*)d_in[1];
    const float* values  = (const float*)d_in[2];
    const float* Wq = (const float*)d_in[3];
    const float* bq = (const float*)d_in[4];
    const float* Wk = (const float*)d_in[5];
    const float* bk = (const float*)d_in[6];
    const float* Wv = (const float*)d_in[7];
    const float* bv = (const float*)d_in[8];
    const float* Wo = (const float*)d_in[9];
    const float* bo = (const float*)d_in[10];

    char* ws = (char*)d_ws;
    size_t off = 0;
    auto alloc = [&](size_t bytes) -> char* {
        char* p = ws + off;
        off += (bytes + 255) & ~(size_t)255;
        return p;
    };
    f16*   values_f16 = (f16*)alloc((size_t)MROWS * DD * 2);  // 33.5 MB
    f16*   Vbuf       = (f16*)alloc((size_t)MROWS * DD * 2);  // 33.5 MB
    f16*   WvT        = (f16*)alloc((size_t)DD * DD * 2);
    f16*   WoT        = (f16*)alloc((size_t)DD * DD * 2);
    float* Wqm_t      = (float*)alloc(HH * DD * 4);
    float* Wkm_t      = (float*)alloc(HH * DD * 4);
    float* bqm        = (float*)alloc(HH * 4);
    float* bkm        = (float*)alloc(HH * 4);
    float* qm         = (float*)alloc((size_t)BB * HH * LL * 4);
    float* km         = (float*)alloc((size_t)BB * HH * LL * 4);
    float* corr       = (float*)alloc((size_t)BB * HH * LL * 4);
    float* wts        = (float*)alloc(BB * HH * KTOP * 4);
    int*   dls        = (int*)alloc(BB * HH * KTOP * 4);
    f16*   out_f16    = values_f16;  // alias: values_f16 is dead after GEMM1

    k_colmeans<<<128, 256, 0, stream>>>(Wq, bq, Wk, bk, Wqm_t, Wkm_t, bqm, bkm);
    k_transpose_cvt<<<dim3(32, 32), dim3(32, 8), 0, stream>>>(Wv, WvT);
    k_transpose_cvt<<<dim3(32, 32), dim3(32, 8), 0, stream>>>(Wo, WoT);
    k_cvt_f16<<<16384, 256, 0, stream>>>(values, values_f16);
    k_means<<<2048, 256, 0, stream>>>(queries, keys, Wqm_t, Wkm_t, bqm, bkm, qm, km);
    k_corr<<<256, 1024, 0, stream>>>(qm, km, corr);
    k_topk<<<64, 256, 0, stream>>>(corr, wts, dls);
    k_gemm_bt<0><<<dim3(MROWS / BM, DD / BN), 256, 0, stream>>>(values_f16, WvT, bv, Vbuf);
    k_roll<<<8192, 256, 0, stream>>>(Vbuf, wts, dls, out_f16);
    k_gemm_bt<1><<<dim3(MROWS / BM, DD / BN), 256, 0, stream>>>(out_f16, WoT, bo, d_out);
}

// Round 5
// 434.426 us; speedup vs baseline: 1.0336x; 1.0064x over previous
//
#include <hip/hip_runtime.h>
#include <hip/hip_bf16.h>
#include <cstdint>

// Problem constants (B, L, D, H from the reference)
#define BB 4
#define LL 4096
#define DD 1024
#define HH 16
#define DKH 64
#define MROWS 16384   // B*L
#define KTOP 8
#define RPB 16        // rows per k_means block

typedef float f32x4 __attribute__((ext_vector_type(4)));
typedef float f32x16 __attribute__((ext_vector_type(16)));
typedef _Float16 f16;
typedef _Float16 f16x4 __attribute__((ext_vector_type(4)));
typedef _Float16 f16x8 __attribute__((ext_vector_type(8)));

// ---------------------------------------------------------------------------
// async global->LDS (16B per lane, wave-uniform LDS base + lane*16)
__device__ __forceinline__ void gll16(const void* g, void* l) {
    __builtin_amdgcn_global_load_lds(
        (const __attribute__((address_space(1))) void*)g,
        (__attribute__((address_space(3))) void*)l, 16, 0, 0);
}

// DPP cross-lane move: returns src value from the partner lane per CTRL.
// 0xB1 = quad_perm(1,0,3,2) -> xor1; 0x4E = quad_perm(2,3,0,1) -> xor2;
// 0x128 = row_ror:8 -> xor8 (rotation by half a 16-row == xor 8).
template <int CTRL>
__device__ __forceinline__ float dppf(float x) {
    return __builtin_bit_cast(float,
        __builtin_amdgcn_update_dpp(0, __builtin_bit_cast(int, x), CTRL, 0xF, 0xF, true));
}

// ---------------------------------------------------------------------------
// Per-head column means of Wq/Wk (mean over DK cols of each head) -> Wqm_t[h][d]
// plus per-head means of bq/bk. Exactness here protects top-k selection.
__global__ void k_colmeans(const float* __restrict__ Wq, const float* __restrict__ bq,
                           const float* __restrict__ Wk, const float* __restrict__ bk,
                           float* __restrict__ Wqm_t, float* __restrict__ Wkm_t,
                           float* __restrict__ bqm, float* __restrict__ bkm) {
    int t = blockIdx.x * blockDim.x + threadIdx.x;   // 0..32767
    int which = t >> 14;                             // 0=q 1=k
    int idx = t & 16383;
    int d = idx >> 4;
    int h = idx & 15;
    const float* W = which ? Wk : Wq;
    const float* p = W + d * DD + h * DKH;
    float s = 0.f;
    #pragma unroll
    for (int c = 0; c < DKH; ++c) s += p[c];
    (which ? Wkm_t : Wqm_t)[h * DD + d] = s * (1.0f / DKH);
    if (d == 0) {
        const float* bb = which ? bk : bq;
        float sb = 0.f;
        for (int c = 0; c < DKH; ++c) sb += bb[h * DKH + c];
        (which ? bkm : bqm)[h] = sb * (1.0f / DKH);
    }
}

// ---------------------------------------------------------------------------
// Transpose 1024x1024 fp32 -> f16 (out[n][k] = in[k][n]) via LDS tile.
__global__ void k_transpose_cvt(const float* __restrict__ in, f16* __restrict__ out) {
    __shared__ float tile[32][33];
    int k0 = blockIdx.x * 32;
    int n0 = blockIdx.y * 32;
    int tx = threadIdx.x, ty = threadIdx.y;
    #pragma unroll
    for (int j = 0; j < 32; j += 8)
        tile[ty + j][tx] = in[(k0 + ty + j) * DD + n0 + tx];
    __syncthreads();
    #pragma unroll
    for (int j = 0; j < 32; j += 8)
        out[(n0 + ty + j) * DD + k0 + tx] = (f16)tile[tx][ty + j];
}

// fp32 -> f16, 4 elems/thread
__global__ void k_cvt_f16(const float* __restrict__ in, f16* __restrict__ out) {
    int i = blockIdx.x * blockDim.x + threadIdx.x;
    f32x4 v = ((const f32x4*)in)[i];
    f16x4 o;
    o[0] = (f16)v.x; o[1] = (f16)v.y; o[2] = (f16)v.z; o[3] = (f16)v.w;
    ((f16x4*)out)[i] = o;
}

// ---------------------------------------------------------------------------
// k_means v4: qm[bh][l], km[bh][l] in fp32.
// Thread (wave w, lane l) owns 4 fixed cols c = w*256 + l*4 and ALL 16 heads.
// W frag = 16 f32x4 = 64 VGPRs, loaded ONCE and pinned in registers via an
// empty asm. DPP butterfly for xor1/xor2/xor8 + one ds_swizzle for xor4.
// Head mapping: lane bits {0,1,3,2} -> head bits {0,1,2,3}.
__global__ __launch_bounds__(256, 4) void k_means(const float* __restrict__ q, const float* __restrict__ k,
                        const float* __restrict__ Wqm_t, const float* __restrict__ Wkm_t,
                        const float* __restrict__ bqm, const float* __restrict__ bkm,
                        float* __restrict__ qm, float* __restrict__ km) {
    __shared__ float lred[RPB * 264];   // 16.9 KB, stride 264 spreads combine banks
    int isK = blockIdx.x & 1;
    int rb  = blockIdx.x >> 1;            // 0..1023
    const float* src = isK ? k : q;
    const float* W   = isK ? Wkm_t : Wqm_t;
    const float* bm  = isK ? bkm : bqm;
    float* dst = isK ? km : qm;
    int t = threadIdx.x;
    int wavei = t >> 6, lane = t & 63;
    int c = wavei * 256 + lane * 4;       // this thread's 4 columns
    f32x4 wr[16];
    #pragma unroll
    for (int h = 0; h < 16; ++h) wr[h] = *(const f32x4*)(W + h * DD + c);
    #pragma unroll
    for (int h = 0; h < 16; ++h) asm volatile("" : "+v"(wr[h]));  // pin in VGPRs
    const float* rbase = src + (size_t)rb * RPB * DD + c;
    f32x4 rv = *(const f32x4*)rbase;
    #pragma unroll
    for (int r = 0; r < RPB; ++r) {
        f32x4 nxt = rv;
        if (r + 1 < RPB) nxt = *(const f32x4*)(rbase + (r + 1) * DD);
        float v[16];
        #pragma unroll
        for (int h = 0; h < 16; ++h)
            v[h] = rv.x * wr[h].x + rv.y * wr[h].y + rv.z * wr[h].z + rv.w * wr[h].w;
        // xor1 (DPP quad_perm): head bit0 = lane bit0
        float u[8];
        #pragma unroll
        for (int i = 0; i < 8; ++i) {
            float keep = (lane & 1) ? v[2*i+1] : v[2*i];
            float send = (lane & 1) ? v[2*i]   : v[2*i+1];
            u[i] = keep + dppf<0xB1>(send);
        }
        // xor2 (DPP quad_perm): head bit1 = lane bit1
        float w2[4];
        #pragma unroll
        for (int i = 0; i < 4; ++i) {
            float keep = (lane & 2) ? u[2*i+1] : u[2*i];
            float send = (lane & 2) ? u[2*i]   : u[2*i+1];
            w2[i] = keep + dppf<0x4E>(send);
        }
        // xor8 (DPP row_ror:8): head bit2 = lane bit3
        float y[2];
        #pragma unroll
        for (int i = 0; i < 2; ++i) {
            float keep = (lane & 8) ? w2[2*i+1] : w2[2*i];
            float send = (lane & 8) ? w2[2*i]   : w2[2*i+1];
            y[i] = keep + dppf<0x128>(send);
        }
        // xor4 (single ds_swizzle): head bit3 = lane bit2
        {
            float keep = (lane & 4) ? y[1] : y[0];
            float send = (lane & 4) ? y[0] : y[1];
            float z = keep + __shfl_xor(send, 4);
            lred[r * 264 + wavei * 64 + lane] = z;
        }
        rv = nxt;
    }
    __syncthreads();
    // combine: 256 outputs (16 rows x 16 heads); sum 4 waves x 4 lane-groups
    int rr = t >> 4, h = t & 15;
    int lp = (h & 3) | (((h >> 2) & 1) << 3) | (((h >> 3) & 1) << 2);
    float s = bm[h];
    #pragma unroll
    for (int w = 0; w < 4; ++w)
        #pragma unroll
        for (int g = 0; g < 4; ++g)
            s += lred[rr * 264 + w * 64 + g * 16 + lp];
    int row = rb * RPB + rr;
    int b = row >> 12, l = row & 4095;
    dst[((size_t)((b << 4) + h) << 12) + l] = s;
}

// ---------------------------------------------------------------------------
// k_corr v4: corr[bh][d] = sum_m qm[bh][(m+d)%L] * km[bh][m]
// 256 blocks x 1024 threads. kv is wave-uniform (scalar path). v3 exposed a
// ~200-cyc dependent s_load stall every 4 m-steps; v4 prefetches the NEXT
// 16-m group of km as one f32x16 (s_load_dwordx16-able) while the current
// group's 64 FMAs run. FMA order identical to v3 (bitwise-same numerics).
__global__ __launch_bounds__(1024) void k_corr(const float* __restrict__ qm,
                                               const float* __restrict__ km,
                                               float* __restrict__ corr) {
    __shared__ float sq[LL];        // 16 KB
    __shared__ f32x4 red[1024];     // 16 KB
    int bh = blockIdx.x >> 2;
    int lag0 = (blockIdx.x & 3) * 1024;
    const f32x4* qg = (const f32x4*)(qm + bh * LL);
    const f32x16* kg16 = (const f32x16*)(km + bh * LL);
    f32x4* sq4 = (f32x4*)sq;
    int t = threadIdx.x;
    for (int i = t; i < LL / 4; i += 1024) sq4[i] = qg[i];
    __syncthreads();
    int lt = t & 255;
    int ms = t >> 8;                 // wave-uniform (wave = 64 lanes, ms flips every 4 waves)
    int d0 = lag0 + lt * 4;
    int m0 = ms * 1024;
    int gi0 = m0 >> 4;               // starting 16-m group (64 groups/thread)
    float a0 = 0, a1 = 0, a2 = 0, a3 = 0;
    f32x4 wv = sq4[((m0 + d0) & 4095) >> 2];
    float w0 = wv.x, w1 = wv.y, w2 = wv.z, w3 = wv.w;
    f32x16 kv = kg16[__builtin_amdgcn_readfirstlane(gi0)];
    for (int g = 0; g < 64; ++g) {
        f32x16 kvn = kv;
        if (g < 63) kvn = kg16[__builtin_amdgcn_readfirstlane(gi0 + g + 1)];
        #pragma unroll
        for (int j = 0; j < 4; ++j) {
            int m = m0 + g * 16 + j * 4;
            f32x4 nx = sq4[((m + 4 + d0) & 4095) >> 2];
            float kx = kv[4*j+0], ky = kv[4*j+1], kz = kv[4*j+2], kw = kv[4*j+3];
            a0 += kx * w0;  a1 += kx * w1;  a2 += kx * w2;  a3 += kx * w3;
            a0 += ky * w1;  a1 += ky * w2;  a2 += ky * w3;  a3 += ky * nx.x;
            a0 += kz * w2;  a1 += kz * w3;  a2 += kz * nx.x; a3 += kz * nx.y;
            a0 += kw * w3;  a1 += kw * nx.x; a2 += kw * nx.y; a3 += kw * nx.z;
            w0 = nx.x; w1 = nx.y; w2 = nx.z; w3 = nx.w;
        }
        kv = kvn;
    }
    f32x4 p; p.x = a0; p.y = a1; p.z = a2; p.w = a3;
    red[t] = p;
    __syncthreads();
    if (t < 256) {
        f32x4 s0 = red[t], s1 = red[256 + t], s2 = red[512 + t], s3 = red[768 + t];
        f32x4 s;
        s.x = s0.x + s1.x + s2.x + s3.x;
        s.y = s0.y + s1.y + s2.y + s3.y;
        s.z = s0.z + s1.z + s2.z + s3.z;
        s.w = s0.w + s1.w + s2.w + s3.w;
        *(f32x4*)(corr + bh * LL + lag0 + t * 4) = s;
    }
}

// ---------------------------------------------------------------------------
// top-8 (value, index) per bh with lowest-index tie-break, then softmax.
__global__ __launch_bounds__(256) void k_topk(const float* __restrict__ corr,
                                              float* __restrict__ wts, int* __restrict__ dls) {
    __shared__ float sc[LL];
    __shared__ float rv[4]; __shared__ int ri[4];
    __shared__ float topv[KTOP]; __shared__ int topi[KTOP];
    int bh = blockIdx.x;
    for (int i = threadIdx.x; i < LL; i += 256) sc[i] = corr[bh * LL + i];
    for (int kk = 0; kk < KTOP; ++kk) {
        __syncthreads();
        float bv = -1e30f; int bi = 0;
        for (int i = threadIdx.x; i < LL; i += 256) {
            float v = sc[i];
            if (v > bv) { bv = v; bi = i; }
        }
        #pragma unroll
        for (int off = 32; off; off >>= 1) {
            float ov = __shfl_down(bv, off);
            int oi = __shfl_down(bi, off);
            if (ov > bv || (ov == bv && oi < bi)) { bv = ov; bi = oi; }
        }
        int wid = threadIdx.x >> 6;
        if ((threadIdx.x & 63) == 0) { rv[wid] = bv; ri[wid] = bi; }
        __syncthreads();
        if (threadIdx.x == 0) {
            for (int w = 1; w < 4; ++w)
                if (rv[w] > bv || (rv[w] == bv && ri[w] < bi)) { bv = rv[w]; bi = ri[w]; }
            topv[kk] = bv; topi[kk] = bi;
            sc[bi] = -1e30f;
        }
    }
    __syncthreads();
    if (threadIdx.x == 0) {
        float mx = topv[0], s = 0.f, e[KTOP];
        #pragma unroll
        for (int kk = 0; kk < KTOP; ++kk) { e[kk] = __expf(topv[kk] - mx); s += e[kk]; }
        float inv = 1.0f / s;
        #pragma unroll
        for (int kk = 0; kk < KTOP; ++kk) {
            wts[bh * KTOP + kk] = e[kk] * inv;
            dls[bh * KTOP + kk] = topi[kk];
        }
    }
}

// ---------------------------------------------------------------------------
// f16 MFMA GEMM v4: C = A(MxK) @ BT(NxK)^T + bias.
// Rounds 1-3 proved the 64x64-per-wave structure is LDS-pipe-bound (3 schedules,
// same 64us, MfmaUtil 21%): 8KB LDS read per wave-K-step vs 1.05 MFLOP.
// v4 geometry fixes the ratio instead of the schedule:
//   - BM=256, BN=128, 4 waves (2M x 2N), per-wave 128x64 (Mr=8 x Nr=4,
//     acc = 128 VGPR): same LDS bytes per wave-K-step, 2x the FLOPs.
//   - B NEVER touches LDS: BT is 2 MB, L2-resident per XCD. B fragments are
//     clean per-lane 16B global loads (col*K + kt*32 + quad*8), prefetched
//     one K-step ahead into registers. Removes B's LDS reads AND stage writes.
// Per block-K-step now: LDS = 16KB A-write + 32KB A-read (~500 cyc) vs
// MFMA 2.1 MFLOP (~620 cyc) -> MFMA-bound for the first time.
// Schedule: plain 2-buffer + one __syncthreads per K-step, manually unrolled
// x2 so buffer indices are compile-time (round-2 lesson: runtime indices cost
// 3x VALU). The sync's vmcnt drain lands after COMPUTE, so stage/B-load
// latency hides under the ~700-cyc MFMA phase.
// LDS A tile [256][32] f16, 16B chunks with XOR swizzle kc^((row>>1)&3)
// applied on the pre-swizzled GLOBAL source (gll16 dest must stay linear);
// fragment ds_read_b128 lands 2-way bank aliased (free).
// Grid: blockIdx.x = M-tile (fastest) -> the 8 N-blocks of an A-panel land on
// one XCD; per XCD 8 panels x 512KB = 4MB = one L2 (round-1 verified).
// MODE 0: store f16 into V[b][h][l][c] (BHLD).  MODE 1: store fp32 row-major.
#define BM 256
#define BN 128
#define BKK 32
template <int MODE>
__global__ __launch_bounds__(256, 2) void k_gemm_bt(const f16* __restrict__ A,
                                                    const f16* __restrict__ BT,
                                                    const float* __restrict__ bias,
                                                    void* __restrict__ Cout) {
    __shared__ f16 As[2][BM * BKK];   // 2 x 16 KB
    const int K = DD;
    int m0 = blockIdx.x * BM;
    int n0 = blockIdx.y * BN;
    int tid = threadIdx.x;
    int lane = tid & 63;
    int wave = tid >> 6;
    int wm = wave & 1, wn = wave >> 1;    // 2M x 2N wave grid

    // ---- A staging: 256 rows x 32 k per buffer, 4 gll16/thread ----
    int rowS = tid >> 2;                  // 0..63
    int slot = tid & 3;
    int kcS = slot ^ ((rowS >> 1) & 3);   // same for rowS+64/128/192 (64%4==0)
    const f16* gA0 = A + (size_t)(m0 + rowS) * K + kcS * 8;
    const f16* gA1 = A + (size_t)(m0 + rowS + 64) * K + kcS * 8;
    const f16* gA2 = A + (size_t)(m0 + rowS + 128) * K + kcS * 8;
    const f16* gA3 = A + (size_t)(m0 + rowS + 192) * K + kcS * 8;

    // ---- fragment offsets ----
    int fr = lane & 15;
    int quad = lane >> 4;
    int a_off[8];
    #pragma unroll
    for (int i = 0; i < 8; ++i) {
        int ra = wm * 128 + i * 16 + fr;
        a_off[i] = (ra * 4 + (quad ^ ((ra >> 1) & 3))) * 8;   // f16 elements
    }
    // B fragment global pointers (per-lane, L2-resident), advance by kt*32
    const f16* gB[4];
    #pragma unroll
    for (int i = 0; i < 4; ++i)
        gB[i] = BT + (size_t)(n0 + wn * 64 + i * 16 + fr) * K + quad * 8;

    f32x4 acc[8][4] = {};
    f16x8 b0[4], b1[4];

    auto STAGE = [&](int buf, int kt) {   // buf compile-time at all call sites
        char* la = (char*)(&As[buf][0]) + wave * 1024;
        int ko = kt * BKK;
        gll16(gA0 + ko, la);
        gll16(gA1 + ko, la + 4096);
        gll16(gA2 + ko, la + 8192);
        gll16(gA3 + ko, la + 12288);
    };
    auto LOADB = [&](f16x8 (&bd)[4], int kt) {
        int ko = kt * BKK;
        #pragma unroll
        for (int i = 0; i < 4; ++i) bd[i] = *(const f16x8*)(gB[i] + ko);
    };
    auto COMPUTE = [&](int buf, f16x8 (&bc)[4]) {
        const f16* Ab = &As[buf][0];
        f16x8 af[8];
        #pragma unroll
        for (int i = 0; i < 8; ++i) af[i] = *(const f16x8*)(Ab + a_off[i]);
        #pragma unroll
        for (int im = 0; im < 8; ++im)
            #pragma unroll
            for (int in = 0; in < 4; ++in)
                acc[im][in] = __builtin_amdgcn_mfma_f32_16x16x32_f16(af[im], bc[in], acc[im][in], 0, 0, 0);
    };

    const int NT = K / BKK;               // 32 (even)
    STAGE(0, 0);
    LOADB(b0, 0);
    __syncthreads();                      // buf0 + b0 ready
    for (int kt = 0; kt < NT - 2; kt += 2) {
        STAGE(1, kt + 1);                 // issue next-tile loads FIRST
        LOADB(b1, kt + 1);
        COMPUTE(0, b0);                   // ~700 cyc of MFMA hides them
        __syncthreads();                  // buf1 + b1 ready; buf0 consumed
        STAGE(0, kt + 2);
        LOADB(b0, kt + 2);
        COMPUTE(1, b1);
        __syncthreads();
    }
    STAGE(1, NT - 1);
    LOADB(b1, NT - 1);
    COMPUTE(0, b0);
    __syncthreads();
    COMPUTE(1, b1);

    // epilogue: C/D layout col = lane&15, row = quad*4 + reg
    #pragma unroll
    for (int in = 0; in < 4; ++in) {
        int col = n0 + wn * 64 + in * 16 + fr;
        float bb = bias[col];
        #pragma unroll
        for (int im = 0; im < 8; ++im) {
            int rowb = m0 + wm * 128 + im * 16 + quad * 4;
            #pragma unroll
            for (int r = 0; r < 4; ++r) {
                float val = acc[im][in][r] + bb;
                if (MODE == 0) {
                    int rr = rowb + r;
                    int b = rr >> 12, l = rr & 4095, h = col >> 6, c = col & 63;
                    ((f16*)Cout)[((size_t)(((b << 4) + h) << 12) + l) * 64 + c] = (f16)val;
                } else {
                    ((float*)Cout)[(size_t)(rowb + r) * DD + col] = val;
                }
            }
        }
    }
}

// ---------------------------------------------------------------------------
// out[b][l][h*64+c] = sum_k w[bh][k] * V[b][h][(l-d_k)&4095][c], f16 in/out.
// XCD-grouped block mapping: each bh's V-slice is 512 KB read 8x (shifted).
// Group all 128 blocks of a bh onto ONE XCD (8 bh per XCD = 4 MB = one L2)
// so each bh is fetched from HBM once chip-wide instead of once per XCD.
__global__ __launch_bounds__(256) void k_roll(const f16* __restrict__ V,
                                              const float* __restrict__ wts,
                                              const int* __restrict__ dls,
                                              f16* __restrict__ out) {
    int x = blockIdx.x;
    int wk = ((x & 7) << 10) | (x >> 3);       // bijective: 8192 = 8 x 1024
    int t = wk * 256 + threadIdx.x;            // B*H*L*8 threads
    int cc = t & 7;
    int l = (t >> 3) & 4095;
    int bh = t >> 15;
    const f16* vb = V + ((size_t)bh << 18);
    float a[8] = {};
    #pragma unroll
    for (int kk = 0; kk < KTOP; ++kk) {
        float w = wts[bh * KTOP + kk];
        int d = dls[bh * KTOP + kk];
        int src = (l - d) & 4095;
        f16x8 vv = *(const f16x8*)(vb + (src << 6) + (cc << 3));
        #pragma unroll
        for (int j = 0; j < 8; ++j) a[j] += w * (float)vv[j];
    }
    f16* o = out + ((size_t)((bh >> 4) << 12) + l) * 1024 + ((bh & 15) << 6) + (cc << 3);
    f16x8 ov;
    #pragma unroll
    for (int j = 0; j < 8; ++j) ov[j] = (f16)a[j];
    *(f16x8*)o = ov;
}

// ---------------------------------------------------------------------------
extern "C" void kernel_launch(void* const* d_in, const int* in_sizes, int n_in,
                              void* d_out, int out_size, void* d_ws, size_t ws_size,
                              hipStream_t stream) {
    const float* queries = (const float*)d_in[0];
    const float* keys    = (const float*)d_in[1];
    const float* values  = (const float*)d_in[2];
    const float* Wq = (const float*)d_in[3];
    const float* bq = (const float*)d_in[4];
    const float* Wk = (const float*)d_in[5];
    const float* bk = (const float*)d_in[6];
    const float* Wv = (const float*)d_in[7];
    const float* bv = (const float*)d_in[8];
    const float* Wo = (const float*)d_in[9];
    const float* bo = (const float*)d_in[10];

    char* ws = (char*)d_ws;
    size_t off = 0;
    auto alloc = [&](size_t bytes) -> char* {
        char* p = ws + off;
        off += (bytes + 255) & ~(size_t)255;
        return p;
    };
    f16*   values_f16 = (f16*)alloc((size_t)MROWS * DD * 2);  // 33.5 MB
    f16*   Vbuf       = (f16*)alloc((size_t)MROWS * DD * 2);  // 33.5 MB
    f16*   WvT        = (f16*)alloc((size_t)DD * DD * 2);
    f16*   WoT        = (f16*)alloc((size_t)DD * DD * 2);
    float* Wqm_t      = (float*)alloc(HH * DD * 4);
    float* Wkm_t      = (float*)alloc(HH * DD * 4);
    float* bqm        = (float*)alloc(HH * 4);
    float* bkm        = (float*)alloc(HH * 4);
    float* qm         = (float*)alloc((size_t)BB * HH * LL * 4);
    float* km         = (float*)alloc((size_t)BB * HH * LL * 4);
    float* corr       = (float*)alloc((size_t)BB * HH * LL * 4);
    float* wts        = (float*)alloc(BB * HH * KTOP * 4);
    int*   dls        = (int*)alloc(BB * HH * KTOP * 4);
    f16*   out_f16    = values_f16;  // alias: values_f16 is dead after GEMM1

    k_colmeans<<<128, 256, 0, stream>>>(Wq, bq, Wk, bk, Wqm_t, Wkm_t, bqm, bkm);
    k_transpose_cvt<<<dim3(32, 32), dim3(32, 8), 0, stream>>>(Wv, WvT);
    k_transpose_cvt<<<dim3(32, 32), dim3(32, 8), 0, stream>>>(Wo, WoT);
    k_cvt_f16<<<16384, 256, 0, stream>>>(values, values_f16);
    k_means<<<2048, 256, 0, stream>>>(queries, keys, Wqm_t, Wkm_t, bqm, bkm, qm, km);
    k_corr<<<256, 1024, 0, stream>>>(qm, km, corr);
    k_topk<<<64, 256, 0, stream>>>(corr, wts, dls);
    k_gemm_bt<0><<<dim3(MROWS / BM, DD / BN), 256, 0, stream>>>(values_f16, WvT, bv, Vbuf);
    k_roll<<<8192, 256, 0, stream>>>(Vbuf, wts, dls, out_f16);
    k_gemm_bt<1><<<dim3(MROWS / BM, DD / BN), 256, 0, stream>>>(out_f16, WoT, bo, d_out);
}